// Round 2
// baseline (139.626 us; speedup 1.0000x reference)
//
#include <hip/hip_runtime.h>

#define B_ITEMS 65536

// ---------- helpers ----------
__device__ __forceinline__ float shx(float v, int m) {
    return __shfl_xor(v, m, 64);
}
__device__ __forceinline__ float shfl64(float v, int s) {
    return __shfl(v, s, 64);
}
__device__ __forceinline__ float rdlane(float v, int l) {
    // broadcast lane l (compile-time constant after unroll) -> SGPR
    return __uint_as_float(__builtin_amdgcn_readlane(__float_as_uint(v), l));
}

// One wave handles FOUR items (g = lane>>4 selects the item whose angles this
// lane stores; ALL 64 lanes participate in every item's statevector).
// Amplitude position p = lane*4 + r; qubit q(0..5) <-> lane bit (5-q);
// qubit 6 <-> r bit 1; qubit 7 <-> r bit 0.
__global__ __launch_bounds__(256) void fused_kernel(
    const float* __restrict__ x, const float* __restrict__ prev,
    const float* __restrict__ W_enc, const float* __restrict__ b_enc,
    const float* __restrict__ W_layer, const float* __restrict__ b_layer,
    const float* __restrict__ W_qubit, const float* __restrict__ b_qubit,
    const float* __restrict__ W_post, const float* __restrict__ b_post,
    float* __restrict__ out, float* __restrict__ params_out)
{
    const int lane  = threadIdx.x & 63;
    const int wave  = blockIdx.x * 4 + (threadIdx.x >> 6);
    const int item0 = wave * 4;
    const int g     = lane >> 4;     // which of the 4 items this lane's angles belong to
    const int j     = lane & 15;     // angle slot within the item
    const int item  = item0 + g;

    // ---- fused prep: res = W_enc x + b; params = lay*qub + prev (redundant per 16-lane group) ----
    float xi[8];
#pragma unroll
    for (int k = 0; k < 8; ++k) xi[k] = x[item * 8 + k];

    float res[8];
#pragma unroll
    for (int r = 0; r < 8; ++r) {
        float acc = b_enc[r];
#pragma unroll
        for (int k = 0; k < 8; ++k) acc = fmaf(W_enc[r * 8 + k], xi[k], acc);
        res[r] = acc;
    }

    const int dd = j >> 3, qq0 = j & 7;
    float lay = b_layer[dd];
    float qub = b_qubit[qq0];
#pragma unroll
    for (int k = 0; k < 8; ++k) lay = fmaf(W_layer[dd * 8 + k], res[k], lay);
#pragma unroll
    for (int k = 0; k < 8; ++k) qub = fmaf(W_qubit[qq0 * 8 + k], res[k], qub);

    const float thetaP = fmaf(lay, qub, prev[item * 16 + j]);
    params_out[item * 16 + j] = thetaP;        // fully coalesced: addr = wave*256B + lane*4B
    const float thetaX = xi[qq0];              // lanes j<8 hold encoding angle x[item*8+j]

    float sX, cX, sP, cP;
    __sincosf(0.5f * thetaX, &sX, &cX);
    __sincosf(0.5f * thetaP, &sP, &cP);

    // ---- statevectors: a[g2][r], 4 items, init |+>^8 = 2^-4 everywhere ----
    float a[4][4];
#pragma unroll
    for (int g2 = 0; g2 < 4; ++g2)
#pragma unroll
        for (int r = 0; r < 4; ++r) a[g2][r] = 0.0625f;

    // bpermute lane sources for the composed CNOT layers (computed once)
    const int srcE = lane ^ ((lane >> 1) & 21);  // CNOT(0,1)(2,3)(4,5)
    const int srcO = lane ^ ((lane >> 1) & 10);  // CNOT(1,2)(3,4)

    auto ry_lane = [&](int g2, float c, float s, int m) {
        const float ss = (lane & m) ? s : -s;
#pragma unroll
        for (int r = 0; r < 4; ++r) {
            const float b = shx(a[g2][r], m);
            a[g2][r] = fmaf(c, a[g2][r], ss * b);
        }
    };
    auto ry_r6 = [&](int g2, float c, float s) {   // qubit 6: pairs (0,2),(1,3)
        const float n0 = fmaf(c, a[g2][0], -s * a[g2][2]);
        const float n2 = fmaf(c, a[g2][2],  s * a[g2][0]);
        const float n1 = fmaf(c, a[g2][1], -s * a[g2][3]);
        const float n3 = fmaf(c, a[g2][3],  s * a[g2][1]);
        a[g2][0] = n0; a[g2][1] = n1; a[g2][2] = n2; a[g2][3] = n3;
    };
    auto ry_r7 = [&](int g2, float c, float s) {   // qubit 7: pairs (0,1),(2,3)
        const float n0 = fmaf(c, a[g2][0], -s * a[g2][1]);
        const float n1 = fmaf(c, a[g2][1],  s * a[g2][0]);
        const float n2 = fmaf(c, a[g2][2], -s * a[g2][3]);
        const float n3 = fmaf(c, a[g2][3],  s * a[g2][2]);
        a[g2][0] = n0; a[g2][1] = n1; a[g2][2] = n2; a[g2][3] = n3;
    };

    // encoding RY round (angles from cX/sX, lanes g2*16 + q)
#pragma unroll
    for (int g2 = 0; g2 < 4; ++g2) {
#pragma unroll
        for (int q = 0; q < 6; ++q)
            ry_lane(g2, rdlane(cX, g2 * 16 + q), rdlane(sX, g2 * 16 + q), 32 >> q);
        ry_r6(g2, rdlane(cX, g2 * 16 + 6), rdlane(sX, g2 * 16 + 6));
        ry_r7(g2, rdlane(cX, g2 * 16 + 7), rdlane(sX, g2 * 16 + 7));
    }

    // two entangling+RY depths (angles from cP/sP, lanes g2*16 + k*8 + q)
#pragma unroll
    for (int k = 0; k < 2; ++k) {
#pragma unroll
        for (int g2 = 0; g2 < 4; ++g2) {
            // CNOT even layer: lane gather + unconditional a2<->a3 swap (CNOT(6,7))
#pragma unroll
            for (int r = 0; r < 4; ++r) a[g2][r] = shfl64(a[g2][r], srcE);
            { const float t = a[g2][2]; a[g2][2] = a[g2][3]; a[g2][3] = t; }
            // CNOT odd layer: lane gather + conditional (a0,a2),(a1,a3) swap (CNOT(5,6))
#pragma unroll
            for (int r = 0; r < 4; ++r) a[g2][r] = shfl64(a[g2][r], srcO);
            const bool f = (lane & 1) != 0;
            const float n0 = f ? a[g2][2] : a[g2][0], n2 = f ? a[g2][0] : a[g2][2];
            const float n1 = f ? a[g2][3] : a[g2][1], n3 = f ? a[g2][1] : a[g2][3];
            a[g2][0] = n0; a[g2][1] = n1; a[g2][2] = n2; a[g2][3] = n3;
            // RY round
#pragma unroll
            for (int q = 0; q < 6; ++q)
                ry_lane(g2, rdlane(cP, g2 * 16 + k * 8 + q),
                            rdlane(sP, g2 * 16 + k * 8 + q), 32 >> q);
            ry_r6(g2, rdlane(cP, g2 * 16 + k * 8 + 6), rdlane(sP, g2 * 16 + k * 8 + 6));
            ry_r7(g2, rdlane(cP, g2 * 16 + k * 8 + 7), rdlane(sP, g2 * 16 + k * 8 + 7));
        }
    }

    // ---- epilogue: out = b_post + sum_lanes prob(lane) * g(lane) ----
    // g(lane) folds all four W_post weights with the Z signs (lane bits 5,4,3,2)
    const float gw = ((lane & 32) ? -W_post[0] : W_post[0])
                   + ((lane & 16) ? -W_post[1] : W_post[1])
                   + ((lane &  8) ? -W_post[2] : W_post[2])
                   + ((lane &  4) ? -W_post[3] : W_post[3]);

    float tot[4];
#pragma unroll
    for (int g2 = 0; g2 < 4; ++g2) {
        float p2 = a[g2][0] * a[g2][0];
#pragma unroll
        for (int r = 1; r < 4; ++r) p2 = fmaf(a[g2][r], a[g2][r], p2);
        float t = p2 * gw;
        t += shx(t, 1);  t += shx(t, 2);  t += shx(t, 4);
        t += shx(t, 8);  t += shx(t, 16); t += shx(t, 32);
        tot[g2] = t;
    }

    if (lane < 4) {
        float v = tot[0];
        if (lane == 1) v = tot[1];
        if (lane == 2) v = tot[2];
        if (lane == 3) v = tot[3];
        out[item0 + lane] = b_post[0] + v;
    }
}

extern "C" void kernel_launch(void* const* d_in, const int* in_sizes, int n_in,
                              void* d_out, int out_size, void* d_ws, size_t ws_size,
                              hipStream_t stream) {
    const float* x       = (const float*)d_in[0];  // [B,8]
    const float* prev    = (const float*)d_in[1];  // [B,2,8]
    const float* W_enc   = (const float*)d_in[2];
    const float* b_enc   = (const float*)d_in[3];
    const float* W_layer = (const float*)d_in[4];
    const float* b_layer = (const float*)d_in[5];
    const float* W_qubit = (const float*)d_in[6];
    const float* b_qubit = (const float*)d_in[7];
    const float* W_post  = (const float*)d_in[8];
    const float* b_post  = (const float*)d_in[9];

    float* out    = (float*)d_out;        // [B,1]
    float* params = out + B_ITEMS;        // [B,2,8] (second output)

    // 4 items/wave, 4 waves/block -> 16 items/block -> 4096 blocks
    fused_kernel<<<B_ITEMS / 16, 256, 0, stream>>>(
        x, prev, W_enc, b_enc, W_layer, b_layer, W_qubit, b_qubit,
        W_post, b_post, out, params);
}

// Round 4
// 121.289 us; speedup vs baseline: 1.1512x; 1.1512x over previous
//
#include <hip/hip_runtime.h>

#define B_ITEMS 65536

// ---------- helpers ----------
__device__ __forceinline__ float shfl64(float v, int s) { return __shfl(v, s, 64); }
__device__ __forceinline__ float rdlane(float v, int l) {
    return __uint_as_float(__builtin_amdgcn_readlane(__float_as_uint(v), l));
}
template <int CTRL>
__device__ __forceinline__ float dppf(float v) {
    return __int_as_float(__builtin_amdgcn_update_dpp(
        __float_as_int(v), __float_as_int(v), CTRL, 0xF, 0xF, false));
}
__device__ __forceinline__ float swz16(float v) {  // lane ^ 16 via ds_swizzle
    return __int_as_float(__builtin_amdgcn_ds_swizzle(__float_as_int(v), 0x401F));
}
// lane ^ 4 via 2 DPP movs + select.
// ISA direction (per GPUOpen DPP scan): row_shr:N -> lane i gets lane i-N;
//                                        row_shl:N -> lane i gets lane i+N.
__device__ __forceinline__ float xor4f(float v, int lane) {
    const float hi = dppf<0x114>(v);  // row_shr:4 -> i-4 (valid where lane&4)
    const float lo = dppf<0x104>(v);  // row_shl:4 -> i+4 (valid where !(lane&4))
    return (lane & 4) ? hi : lo;
}

// shuffle-by-xor-mask, mapped to the cheapest pipe per mask
#define SH32(v) __shfl_xor((v), 32, 64)   // DS bpermute
#define SH16(v) swz16(v)                  // DS swizzle
#define SH8(v)  dppf<0x128>(v)            // DPP row_ror:8 (rot8 in 16-row == xor8)
#define SH4(v)  xor4f((v), lane)          // DPP combo      (VALU)
#define SH2(v)  dppf<0x4E>(v)             // DPP quad_perm [2,3,0,1]
#define SH1(v)  dppf<0xB1>(v)             // DPP quad_perm [1,0,3,2]

// RY on lane-bit qubit with mask M; angle broadcast from lane LB
#define RY_LANEQ(LB, M, SHUF) { \
    const float c = rdlane(cv, (LB)); \
    const float s = rdlane(sv, (LB)); \
    const float ss = (lane & (M)) ? s : -s; \
    const float b0 = SHUF(a0); const float b1 = SHUF(a1); \
    const float b2 = SHUF(a2); const float b3 = SHUF(a3); \
    a0 = fmaf(c, a0, ss * b0); a1 = fmaf(c, a1, ss * b1); \
    a2 = fmaf(c, a2, ss * b2); a3 = fmaf(c, a3, ss * b3); }

// RY on qubit 6 (reg bit 1): pairs (a0,a2),(a1,a3)
#define RY_R6(LB) { \
    const float c = rdlane(cv, (LB)), s = rdlane(sv, (LB)); \
    const float n0 = fmaf(c, a0, -s * a2), n2 = fmaf(c, a2, s * a0); \
    const float n1 = fmaf(c, a1, -s * a3), n3 = fmaf(c, a3, s * a1); \
    a0 = n0; a1 = n1; a2 = n2; a3 = n3; }

// RY on qubit 7 (reg bit 0): pairs (a0,a1),(a2,a3)
#define RY_R7(LB) { \
    const float c = rdlane(cv, (LB)), s = rdlane(sv, (LB)); \
    const float n0 = fmaf(c, a0, -s * a1), n1 = fmaf(c, a1, s * a0); \
    const float n2 = fmaf(c, a2, -s * a3), n3 = fmaf(c, a3, s * a2); \
    a0 = n0; a1 = n1; a2 = n2; a3 = n3; }

#define RY_ROUND(G) \
    RY_LANEQ((G)+0, 32, SH32) RY_LANEQ((G)+1, 16, SH16) \
    RY_LANEQ((G)+2,  8, SH8 ) RY_LANEQ((G)+3,  4, SH4 ) \
    RY_LANEQ((G)+4,  2, SH2 ) RY_LANEQ((G)+5,  1, SH1 ) \
    RY_R6((G)+6) RY_R7((G)+7)

// Even CNOT layer (0,1)(2,3)(4,5): one composed bpermute gather; (6,7): reg swap
#define CNOT_EVEN { \
    a0 = shfl64(a0, srcE); a1 = shfl64(a1, srcE); \
    a2 = shfl64(a2, srcE); a3 = shfl64(a3, srcE); \
    const float t = a2; a2 = a3; a3 = t; }

// Odd CNOT layer (1,2)(3,4)(5,6): DPP conditional swaps, zero DS
#define CNOT_ODD { \
    { const float t0 = SH8(a0), t1 = SH8(a1), t2 = SH8(a2), t3 = SH8(a3); \
      const bool f = (lane & 16) != 0; \
      a0 = f ? t0 : a0; a1 = f ? t1 : a1; a2 = f ? t2 : a2; a3 = f ? t3 : a3; } \
    { const float t0 = SH2(a0), t1 = SH2(a1), t2 = SH2(a2), t3 = SH2(a3); \
      const bool f = (lane & 4) != 0; \
      a0 = f ? t0 : a0; a1 = f ? t1 : a1; a2 = f ? t2 : a2; a3 = f ? t3 : a3; } \
    { const bool f = (lane & 1) != 0; \
      const float n0 = f ? a2 : a0, n2 = f ? a0 : a2; \
      const float n1 = f ? a3 : a1, n3 = f ? a1 : a3; \
      a0 = n0; a1 = n1; a2 = n2; a3 = n3; } }

// ---------- kernel 0: compose the affine maps (runs once per call, 1 tiny block) ----------
// ws layout (floats): [0:16) W_lay_eff(2x8), [16:18) b_lay_eff,
//                     [32:96) W_qub_eff(8x8), [96:104) b_qub_eff
__global__ void compose_kernel(
    const float* __restrict__ W_enc, const float* __restrict__ b_enc,
    const float* __restrict__ W_layer, const float* __restrict__ b_layer,
    const float* __restrict__ W_qubit, const float* __restrict__ b_qubit,
    float* __restrict__ ws)
{
    const int t = threadIdx.x;
    if (t < 16) {                       // W_lay_eff = W_layer @ W_enc
        const int d = t >> 3, c = t & 7;
        float acc = 0.0f;
#pragma unroll
        for (int r = 0; r < 8; ++r) acc = fmaf(W_layer[d * 8 + r], W_enc[r * 8 + c], acc);
        ws[t] = acc;
    } else if (t < 18) {                // b_lay_eff = W_layer @ b_enc + b_layer
        const int d = t - 16;
        float acc = b_layer[d];
#pragma unroll
        for (int r = 0; r < 8; ++r) acc = fmaf(W_layer[d * 8 + r], b_enc[r], acc);
        ws[16 + d] = acc;
    } else if (t < 82) {                // W_qub_eff = W_qubit @ W_enc
        const int e = t - 18, r = e >> 3, c = e & 7;
        float acc = 0.0f;
#pragma unroll
        for (int k = 0; k < 8; ++k) acc = fmaf(W_qubit[r * 8 + k], W_enc[k * 8 + c], acc);
        ws[32 + e] = acc;
    } else if (t < 90) {                // b_qub_eff = W_qubit @ b_enc + b_qubit
        const int r = t - 82;
        float acc = b_qubit[r];
#pragma unroll
        for (int k = 0; k < 8; ++k) acc = fmaf(W_qubit[r * 8 + k], b_enc[k], acc);
        ws[96 + r] = acc;
    }
}

// ---------- kernel 1: fused prep + simulation, ONE item per wave ----------
// Amplitude p = lane*4 + r; qubit q(0..5) <-> lane bit (5-q); q6 <-> r bit1; q7 <-> r bit0.
// Angle lanes: 0..7 encoding RY (= x), 8..23 weight RY (j = lane-8 = d*8+q).
__global__ __launch_bounds__(256) void fused_kernel(
    const float* __restrict__ x, const float* __restrict__ prev,
    const float* __restrict__ wcomp,
    const float* __restrict__ W_post, const float* __restrict__ b_post,
    float* __restrict__ out, float* __restrict__ params_out)
{
    const int lane = threadIdx.x & 63;
    const int item = blockIdx.x * 4 + (threadIdx.x >> 6);

    // ---- prep via composed affine maps ----
    const int j  = (lane - 8) & 15;     // lanes 8..23 -> 0..15; others -> harmless alias
    const int dd = j >> 3, qq = j & 7;

    const float4 xa = *(const float4*)(x + item * 8);
    const float4 xb = *(const float4*)(x + item * 8 + 4);
    const float4 wl0 = *(const float4*)(wcomp + dd * 8);
    const float4 wl1 = *(const float4*)(wcomp + dd * 8 + 4);
    const float4 wq0 = *(const float4*)(wcomp + 32 + qq * 8);
    const float4 wq1 = *(const float4*)(wcomp + 32 + qq * 8 + 4);

    float lay = wcomp[16 + dd];
    lay = fmaf(wl0.x, xa.x, lay); lay = fmaf(wl0.y, xa.y, lay);
    lay = fmaf(wl0.z, xa.z, lay); lay = fmaf(wl0.w, xa.w, lay);
    lay = fmaf(wl1.x, xb.x, lay); lay = fmaf(wl1.y, xb.y, lay);
    lay = fmaf(wl1.z, xb.z, lay); lay = fmaf(wl1.w, xb.w, lay);

    float qub = wcomp[96 + qq];
    qub = fmaf(wq0.x, xa.x, qub); qub = fmaf(wq0.y, xa.y, qub);
    qub = fmaf(wq0.z, xa.z, qub); qub = fmaf(wq0.w, xa.w, qub);
    qub = fmaf(wq1.x, xb.x, qub); qub = fmaf(wq1.y, xb.y, qub);
    qub = fmaf(wq1.z, xb.z, qub); qub = fmaf(wq1.w, xb.w, qub);

    const float thetaP = fmaf(lay, qub, prev[item * 16 + j]);
    if (lane >= 8 && lane < 24) params_out[item * 16 + j] = thetaP;

    const float thetaX = x[item * 8 + (lane & 7)];
    const float theta  = (lane < 8) ? thetaX : thetaP;

    float sv, cv;
    __sincosf(0.5f * theta, &sv, &cv);

    // ---- statevector ----
    float a0 = 0.0625f, a1 = 0.0625f, a2 = 0.0625f, a3 = 0.0625f;  // |+>^8
    const int srcE = lane ^ ((lane >> 1) & 21);

    RY_ROUND(0)
    CNOT_EVEN CNOT_ODD RY_ROUND(8)
    CNOT_EVEN CNOT_ODD RY_ROUND(16)

    // ---- epilogue: out = b_post + sum_lanes prob * gw(lane), all-DPP reduction ----
    const float gw = ((lane & 32) ? -W_post[0] : W_post[0])
                   + ((lane & 16) ? -W_post[1] : W_post[1])
                   + ((lane &  8) ? -W_post[2] : W_post[2])
                   + ((lane &  4) ? -W_post[3] : W_post[3]);

    float t = a0 * a0;
    t = fmaf(a1, a1, t); t = fmaf(a2, a2, t); t = fmaf(a3, a3, t);
    t *= gw;
    t += dppf<0x128>(t);  // + ror:8  (16-row rotate-reduce)
    t += dppf<0x124>(t);  // + ror:4
    t += dppf<0x122>(t);  // + ror:2
    t += dppf<0x121>(t);  // + ror:1  -> full row-of-16 sum in every lane
    const float r0 = rdlane(t, 0),  r1 = rdlane(t, 16);
    const float r2 = rdlane(t, 32), r3 = rdlane(t, 48);
    if (lane == 0) out[item] = b_post[0] + ((r0 + r1) + (r2 + r3));
}

extern "C" void kernel_launch(void* const* d_in, const int* in_sizes, int n_in,
                              void* d_out, int out_size, void* d_ws, size_t ws_size,
                              hipStream_t stream) {
    const float* x       = (const float*)d_in[0];  // [B,8]
    const float* prev    = (const float*)d_in[1];  // [B,2,8]
    const float* W_enc   = (const float*)d_in[2];
    const float* b_enc   = (const float*)d_in[3];
    const float* W_layer = (const float*)d_in[4];
    const float* b_layer = (const float*)d_in[5];
    const float* W_qubit = (const float*)d_in[6];
    const float* b_qubit = (const float*)d_in[7];
    const float* W_post  = (const float*)d_in[8];
    const float* b_post  = (const float*)d_in[9];

    float* out    = (float*)d_out;     // [B,1]
    float* params = out + B_ITEMS;     // [B,2,8] (second output)
    float* wcomp  = (float*)d_ws;      // 104 floats of composed weights

    compose_kernel<<<1, 128, 0, stream>>>(
        W_enc, b_enc, W_layer, b_layer, W_qubit, b_qubit, wcomp);

    // 1 item/wave, 4 waves/block -> 16384 blocks
    fused_kernel<<<B_ITEMS / 4, 256, 0, stream>>>(
        x, prev, wcomp, W_post, b_post, out, params);
}

// Round 5
// 76.279 us; speedup vs baseline: 1.8305x; 1.5901x over previous
//
#include <hip/hip_runtime.h>

#define B_ITEMS 65536

// Closed-form evaluation of the 8-qubit circuit via Pauli backpropagation.
// Backward conj rules (RY(theta) matrix uses half-angle; Heisenberg uses full):
//   Z -> cos(t) Z - sin(t) X ;  X -> cos(t) X + sin(t) Z
//   CNOT(c,t): Xc->XcXt, Zt->ZcZt, Xt->Xt, Zc->Zc
// Strings with Y factors pruned (<Y>=0 on real states). Evaluate on the
// post-encoding product state: X_q -> cos(x_q), Z_q -> -sin(x_q).
// Result: <Z0>=5 terms, <Z1>,<Z2>,<Z3>=8 terms each (29 total).
// Verified vs forward simulation at weights=0 (general x) and at
// x=pi/2 with w0=pi / w1=pi / w10=pi/2 branch-exercising configs.
__global__ __launch_bounds__(256) void poly_kernel(
    const float* __restrict__ x, const float* __restrict__ prev,
    const float* __restrict__ W_enc, const float* __restrict__ b_enc,
    const float* __restrict__ W_layer, const float* __restrict__ b_layer,
    const float* __restrict__ W_qubit, const float* __restrict__ b_qubit,
    const float* __restrict__ W_post, const float* __restrict__ b_post,
    float* __restrict__ out, float* __restrict__ params_out)
{
    const int i = blockIdx.x * 256 + threadIdx.x;

    float xi[8];
    {
        const float4 xa = *(const float4*)(x + i * 8);
        const float4 xb = *(const float4*)(x + i * 8 + 4);
        xi[0] = xa.x; xi[1] = xa.y; xi[2] = xa.z; xi[3] = xa.w;
        xi[4] = xb.x; xi[5] = xb.y; xi[6] = xb.z; xi[7] = xb.w;
    }

    // ---- prep: res = W_enc x + b_enc; lay = W_layer res + b; qub = W_qubit res + b ----
    float res[8];
#pragma unroll
    for (int r = 0; r < 8; ++r) {
        float acc = b_enc[r];
#pragma unroll
        for (int k = 0; k < 8; ++k) acc = fmaf(W_enc[r * 8 + k], xi[k], acc);
        res[r] = acc;
    }
    float lay[2];
#pragma unroll
    for (int d = 0; d < 2; ++d) {
        float acc = b_layer[d];
#pragma unroll
        for (int k = 0; k < 8; ++k) acc = fmaf(W_layer[d * 8 + k], res[k], acc);
        lay[d] = acc;
    }
    float qub[8];
#pragma unroll
    for (int q = 0; q < 8; ++q) {
        float acc = b_qubit[q];
#pragma unroll
        for (int k = 0; k < 8; ++k) acc = fmaf(W_qubit[q * 8 + k], res[k], acc);
        qub[q] = acc;
    }

    // ---- circuit params (second output): th[k*8+q] ----
    float th[16];
#pragma unroll
    for (int d = 0; d < 2; ++d)
#pragma unroll
        for (int q = 0; q < 8; ++q)
            th[d * 8 + q] = fmaf(lay[d], qub[q], prev[i * 16 + d * 8 + q]);

    {   // coalesced 64 B/thread store
        float4* po = (float4*)(params_out + i * 16);
        po[0] = make_float4(th[0],  th[1],  th[2],  th[3]);
        po[1] = make_float4(th[4],  th[5],  th[6],  th[7]);
        po[2] = make_float4(th[8],  th[9],  th[10], th[11]);
        po[3] = make_float4(th[12], th[13], th[14], th[15]);
    }

    // ---- trig (full angles; light cone needs only 18 of 24) ----
    float cx[8], sx[8];
#pragma unroll
    for (int q = 0; q < 8; ++q) __sincosf(xi[q], &sx[q], &cx[q]);
    float c0[6], s0[6];
#pragma unroll
    for (int q = 0; q < 6; ++q) __sincosf(th[q], &s0[q], &c0[q]);
    float c1[4], s1[4];
#pragma unroll
    for (int p = 0; p < 4; ++p) __sincosf(th[8 + p], &s1[p], &c1[p]);

    // ---- 29-term closed form ----
    float z0 = 0.0f;
    z0 -= c1[0]*c0[0]*sx[0];
    z0 -= c1[0]*s0[0]*cx[0]*cx[1];
    z0 -= s1[0]*c0[0]*c0[1]*cx[0]*cx[2]*cx[3];
    z0 += s1[0]*s0[0]*c0[1]*sx[0]*cx[1]*cx[2]*cx[3];
    z0 += s1[0]*s0[0]*s0[1]*sx[1];

    float z1 = 0.0f;
    z1 -= c1[1]*c0[0]*c0[1]*sx[1];
    z1 += c1[1]*c0[0]*s0[1]*sx[0]*cx[1]*cx[2]*cx[3];
    z1 += c1[1]*s0[0]*s0[1]*cx[0]*cx[2]*cx[3];
    z1 -= s1[1]*c0[1]*c0[2]*c0[3]*cx[1]*cx[3]*cx[4]*cx[5];
    z1 -= s1[1]*c0[1]*c0[2]*s0[3]*cx[1]*sx[2]*sx[3];
    z1 -= s1[1]*s0[1]*c0[2]*c0[3]*sx[0]*sx[1]*cx[2]*cx[4]*cx[5];
    z1 += s1[1]*s0[1]*s0[2]*c0[3]*sx[2]*cx[3]*cx[4]*cx[5];
    z1 += s1[1]*s0[1]*s0[2]*s0[3]*sx[3];

    float z2 = 0.0f;
    z2 += c1[2]*c0[0]*c0[1]*c0[2]*sx[0]*sx[2];
    z2 += c1[2]*c0[0]*c0[1]*s0[2]*sx[1]*cx[2]*cx[3];
    z2 -= c1[2]*c0[0]*s0[1]*s0[2]*sx[0]*cx[1];
    z2 += c1[2]*s0[0]*c0[1]*c0[2]*cx[0]*cx[1]*sx[2];
    z2 -= c1[2]*s0[0]*s0[1]*s0[2]*cx[0];
    z2 -= s1[2]*c0[2]*c0[3]*cx[2]*cx[4]*cx[5];
    z2 += s1[2]*s0[2]*c0[3]*sx[0]*sx[1]*sx[2]*cx[3]*cx[4]*cx[5];
    z2 += s1[2]*s0[2]*s0[3]*sx[0]*sx[1]*sx[3];

    float z3 = 0.0f;
    z3 -= c1[3]*c0[2]*c0[3]*sx[0]*sx[1]*sx[3];
    z3 += c1[3]*c0[2]*s0[3]*sx[0]*sx[1]*sx[2]*cx[3]*cx[4]*cx[5];
    z3 += c1[3]*s0[2]*s0[3]*cx[2]*cx[4]*cx[5];
    z3 -= s1[3]*c0[3]*c0[4]*c0[5]*cx[3]*cx[5]*cx[6]*cx[7];
    z3 -= s1[3]*c0[3]*c0[4]*s0[5]*cx[3]*sx[4]*sx[5];
    z3 -= s1[3]*s0[3]*c0[4]*c0[5]*sx[2]*sx[3]*cx[4]*cx[6]*cx[7];
    z3 += s1[3]*s0[3]*s0[4]*c0[5]*sx[4]*cx[5]*cx[6]*cx[7];
    z3 += s1[3]*s0[3]*s0[4]*s0[5]*sx[5];

    float o = b_post[0];
    o = fmaf(W_post[0], z0, o);
    o = fmaf(W_post[1], z1, o);
    o = fmaf(W_post[2], z2, o);
    o = fmaf(W_post[3], z3, o);
    out[i] = o;
}

extern "C" void kernel_launch(void* const* d_in, const int* in_sizes, int n_in,
                              void* d_out, int out_size, void* d_ws, size_t ws_size,
                              hipStream_t stream) {
    const float* x       = (const float*)d_in[0];  // [B,8]
    const float* prev    = (const float*)d_in[1];  // [B,2,8]
    const float* W_enc   = (const float*)d_in[2];
    const float* b_enc   = (const float*)d_in[3];
    const float* W_layer = (const float*)d_in[4];
    const float* b_layer = (const float*)d_in[5];
    const float* W_qubit = (const float*)d_in[6];
    const float* b_qubit = (const float*)d_in[7];
    const float* W_post  = (const float*)d_in[8];
    const float* b_post  = (const float*)d_in[9];

    float* out    = (float*)d_out;     // [B,1]
    float* params = out + B_ITEMS;     // [B,2,8] (second output)

    // one item per thread: 256 blocks x 256 threads = 65536
    poly_kernel<<<B_ITEMS / 256, 256, 0, stream>>>(
        x, prev, W_enc, b_enc, W_layer, b_layer, W_qubit, b_qubit,
        W_post, b_post, out, params);
}